// Round 1
// baseline (1143.533 us; speedup 1.0000x reference)
//
#include <hip/hip_runtime.h>

// GeneticDosageGNN: 3x GraphConv(+BN+ReLU) -> mean pool -> linear head
// N=50000 nodes, E=800000 edges, dims 128->256->128->64->3, 64 graphs.

constexpr int TS = 64;   // GEMM tile (rows=nodes, cols=features)
constexpr int BKK = 32;  // GEMM K-tile

// ---------------- CSR build ----------------

__global__ __launch_bounds__(256)
void hist_kernel(const int* __restrict__ dst, int* __restrict__ cnt, int E) {
    int i = blockIdx.x * blockDim.x + threadIdx.x;
    if (i < E) atomicAdd(&cnt[dst[i]], 1);
}

__global__ void scan_kernel(const int* __restrict__ cnt, int* __restrict__ rowptr,
                            int* __restrict__ pos, int N) {
    __shared__ int sums[1024];
    int t = threadIdx.x;
    int chunk = (N + 1023) / 1024;
    int b = t * chunk;
    int e = min(b + chunk, N);
    int s = 0;
    for (int i = b; i < e; ++i) s += cnt[i];
    sums[t] = s;
    __syncthreads();
    for (int d = 1; d < 1024; d <<= 1) {
        int val = (t >= d) ? sums[t - d] : 0;
        __syncthreads();
        sums[t] += val;
        __syncthreads();
    }
    int run = (t == 0) ? 0 : sums[t - 1];
    for (int i = b; i < e; ++i) {
        rowptr[i] = run;
        pos[i] = run;
        run += cnt[i];
    }
    if (t == 1023) rowptr[N] = run;
}

__global__ __launch_bounds__(256)
void scatter_kernel(const int* __restrict__ src, const int* __restrict__ dst,
                    int* __restrict__ pos, int* __restrict__ srcs, int E) {
    int i = blockIdx.x * blockDim.x + threadIdx.x;
    if (i < E) {
        int p = atomicAdd(&pos[dst[i]], 1);
        srcs[p] = src[i];
    }
}

// ---------------- aggregation (+optional root/bias/BN/ReLU) ----------------
// One 64-lane wave per node. F = 64 or 128 features.

__global__ __launch_bounds__(256)
void agg_combine(const float* __restrict__ ysrc,   // [N,F] gathered over edges
                 const float* __restrict__ yroot,  // nullable [N,F]
                 const int* __restrict__ rowptr,
                 const int* __restrict__ srcs,
                 const float* __restrict__ bias,   // nullable [F]
                 const float* __restrict__ bng, const float* __restrict__ bnb,
                 const float* __restrict__ bnm, const float* __restrict__ bnv,
                 float* __restrict__ out, int N, int F)
{
    int w = (blockIdx.x * blockDim.x + threadIdx.x) >> 6;
    int lane = threadIdx.x & 63;
    if (w >= N) return;
    int beg = rowptr[w], end = rowptr[w + 1];
    float acc0 = 0.f, acc1 = 0.f;
    for (int e = beg; e < end; ++e) {
        int s = srcs[e];
        const float* p = ysrc + (size_t)s * F;
        acc0 += p[lane];
        if (F == 128) acc1 += p[64 + lane];
    }
#pragma unroll
    for (int h = 0; h < 2; ++h) {
        if (h == 1 && F == 64) break;
        int f = lane + h * 64;
        float val = (h == 0) ? acc0 : acc1;
        if (yroot) val += yroot[(size_t)w * F + f];
        if (bias) val += bias[f];
        if (bng) {
            val = (val - bnm[f]) * rsqrtf(bnv[f] + 1e-5f) * bng[f] + bnb[f];
            val = fmaxf(val, 0.f);
        }
        out[(size_t)w * F + f] = val;
    }
}

// ---------------- fused GEMM: C = act(A1@W1 [+ A2@W2] [+bias] [BN+ReLU]) ----

__global__ __launch_bounds__(256)
void gemm_bn(const float* __restrict__ A1, const float* __restrict__ A2,
             const float* __restrict__ W1, const float* __restrict__ W2,
             const float* __restrict__ bias,
             const float* __restrict__ bng, const float* __restrict__ bnb,
             const float* __restrict__ bnm, const float* __restrict__ bnv,
             float* __restrict__ C, int N, int K, int M)
{
    __shared__ float As[BKK][TS];
    __shared__ float Ws[BKK][TS];
    const int n0 = blockIdx.x * TS;
    const int m0 = blockIdx.y * TS;
    const int tid = threadIdx.x;
    const int tx = tid & 15, ty = tid >> 4;
    float acc[4][4] = {};
    const int nsrc = A2 ? 2 : 1;
    for (int s = 0; s < nsrc; ++s) {
        const float* __restrict__ A = s ? A2 : A1;
        const float* __restrict__ W = s ? W2 : W1;
        for (int k0 = 0; k0 < K; k0 += BKK) {
            __syncthreads();
            // A tile: 64 rows x 32 k, stored transposed As[k][row]
#pragma unroll
            for (int p = 0; p < 2; ++p) {
                int row = (tid >> 3) + p * 32;
                int kq = (tid & 7) * 4;
                int n = n0 + row;
                float4 a = make_float4(0.f, 0.f, 0.f, 0.f);
                if (n < N) a = *(const float4*)(A + (size_t)n * K + k0 + kq);
                As[kq + 0][row] = a.x;
                As[kq + 1][row] = a.y;
                As[kq + 2][row] = a.z;
                As[kq + 3][row] = a.w;
            }
            // W tile: 32 k x 64 cols
#pragma unroll
            for (int p = 0; p < 2; ++p) {
                int k = (tid >> 4) + p * 16;
                int mq = (tid & 15) * 4;
                *(float4*)&Ws[k][mq] = *(const float4*)(W + (size_t)(k0 + k) * M + m0 + mq);
            }
            __syncthreads();
#pragma unroll
            for (int k = 0; k < BKK; ++k) {
                float4 a = *(const float4*)&As[k][ty * 4];
                float4 w = *(const float4*)&Ws[k][tx * 4];
                float av[4] = {a.x, a.y, a.z, a.w};
                float wv[4] = {w.x, w.y, w.z, w.w};
#pragma unroll
                for (int i = 0; i < 4; ++i)
#pragma unroll
                    for (int j = 0; j < 4; ++j)
                        acc[i][j] = fmaf(av[i], wv[j], acc[i][j]);
            }
        }
    }
#pragma unroll
    for (int i = 0; i < 4; ++i) {
        int n = n0 + ty * 4 + i;
        if (n >= N) continue;
#pragma unroll
        for (int j = 0; j < 4; ++j) {
            int mm = m0 + tx * 4 + j;
            float val = acc[i][j];
            if (bias) val += bias[mm];
            if (bng) {
                val = (val - bnm[mm]) * rsqrtf(bnv[mm] + 1e-5f) * bng[mm] + bnb[mm];
                val = fmaxf(val, 0.f);
            }
            C[(size_t)n * M + mm] = val;
        }
    }
}

// ---------------- pooling + head ----------------

__global__ __launch_bounds__(256)
void pool_kernel(const float* __restrict__ h, const int* __restrict__ batch,
                 float* __restrict__ pooled, float* __restrict__ cntg, int N) {
    int i = blockIdx.x * blockDim.x + threadIdx.x;
    if (i >= N * 64) return;
    int n = i >> 6, f = i & 63;
    int g = batch[n];
    atomicAdd(&pooled[g * 64 + f], h[i]);
    if (f == 0) atomicAdd(&cntg[g], 1.0f);
}

__global__ __launch_bounds__(256)
void head_kernel(const float* __restrict__ pooled, const float* __restrict__ cntg,
                 const float* __restrict__ Wout, const float* __restrict__ bout,
                 float* __restrict__ out) {
    int t = threadIdx.x;
    if (t >= 64 * 3) return;
    int g = t / 3, o = t % 3;
    float acc = 0.f;
#pragma unroll
    for (int k = 0; k < 64; ++k) acc += pooled[g * 64 + k] * Wout[k * 3 + o];
    out[t] = acc / fmaxf(cntg[g], 1.0f) + bout[o];
}

// ---------------- launch ----------------

extern "C" void kernel_launch(void* const* d_in, const int* in_sizes, int n_in,
                              void* d_out, int out_size, void* d_ws, size_t ws_size,
                              hipStream_t stream)
{
    const float* x       = (const float*)d_in[0];
    const int*   ei      = (const int*)d_in[1];
    const int*   batch   = (const int*)d_in[2];
    const float* W_rel0  = (const float*)d_in[3];
    const float* b_rel0  = (const float*)d_in[4];
    const float* W_root0 = (const float*)d_in[5];
    const float* bn_g0   = (const float*)d_in[6];
    const float* bn_b0   = (const float*)d_in[7];
    const float* bn_m0   = (const float*)d_in[8];
    const float* bn_v0   = (const float*)d_in[9];
    const float* W_rel1  = (const float*)d_in[10];
    const float* b_rel1  = (const float*)d_in[11];
    const float* W_root1 = (const float*)d_in[12];
    const float* bn_g1   = (const float*)d_in[13];
    const float* bn_b1   = (const float*)d_in[14];
    const float* bn_m1   = (const float*)d_in[15];
    const float* bn_v1   = (const float*)d_in[16];
    const float* W_rel2  = (const float*)d_in[17];
    const float* b_rel2  = (const float*)d_in[18];
    const float* W_root2 = (const float*)d_in[19];
    const float* bn_g2   = (const float*)d_in[20];
    const float* bn_b2   = (const float*)d_in[21];
    const float* bn_m2   = (const float*)d_in[22];
    const float* bn_v2   = (const float*)d_in[23];
    const float* W_out   = (const float*)d_in[24];
    const float* b_out   = (const float*)d_in[25];

    const int N = in_sizes[0] / 128;
    const int E = in_sizes[1] / 2;
    const int* src = ei;
    const int* dst = ei + E;

    char* ws = (char*)d_ws;
    size_t off = 0;
    auto alloc = [&](size_t b) -> void* {
        off = (off + 255) & ~(size_t)255;
        void* p = ws + off;
        off += b;
        return p;
    };

    float* h0    = (float*)alloc((size_t)N * 256 * 4);  // layer0 out; reused as h2 [N,64]
    float* yrel  = (float*)alloc((size_t)N * 128 * 4);  // rel-GEMM out (L1: [N,128], L2: [N,64])
    float* yroot = (float*)alloc((size_t)N * 128 * 4);  // root-GEMM out
    float* aggb  = (float*)alloc((size_t)N * 128 * 4);  // agg0 in L0; h1 [N,128] in L1
    int*   cnt   = (int*)alloc((size_t)N * 4);
    int*   rowp  = (int*)alloc((size_t)(N + 1) * 4);
    int*   pos   = (int*)alloc((size_t)N * 4);
    int*   srcs  = (int*)alloc((size_t)E * 4);
    float* pooled = (float*)alloc((64 * 64 + 64) * 4);
    float* cntg   = pooled + 64 * 64;

    hipMemsetAsync(cnt, 0, (size_t)N * 4, stream);
    hipMemsetAsync(pooled, 0, (64 * 64 + 64) * 4, stream);

    const int TB = 256;
    const int egrid = (E + TB - 1) / TB;
    const int nwb = (N + 3) / 4;  // 4 waves (nodes) per 256-thread block

    hist_kernel<<<egrid, TB, 0, stream>>>(dst, cnt, E);
    scan_kernel<<<1, 1024, 0, stream>>>(cnt, rowp, pos, N);
    scatter_kernel<<<egrid, TB, 0, stream>>>(src, dst, pos, srcs, E);

    // ---- layer 0: agg x (128) first, then [agg|x] @ [Wrel;Wroot] + b, BN, ReLU
    agg_combine<<<nwb, TB, 0, stream>>>(x, nullptr, rowp, srcs,
                                        nullptr, nullptr, nullptr, nullptr, nullptr,
                                        aggb, N, 128);
    {
        dim3 g((N + TS - 1) / TS, 256 / TS);
        gemm_bn<<<g, TB, 0, stream>>>(aggb, x, W_rel0, W_root0, b_rel0,
                                      bn_g0, bn_b0, bn_m0, bn_v0, h0, N, 128, 256);
    }

    // ---- layer 1: yrel/yroot = h0 @ Wrel1/Wroot1, then agg(yrel)+yroot+b, BN, ReLU
    {
        dim3 g((N + TS - 1) / TS, 128 / TS);
        gemm_bn<<<g, TB, 0, stream>>>(h0, nullptr, W_rel1, nullptr, nullptr,
                                      nullptr, nullptr, nullptr, nullptr, yrel, N, 256, 128);
        gemm_bn<<<g, TB, 0, stream>>>(h0, nullptr, W_root1, nullptr, nullptr,
                                      nullptr, nullptr, nullptr, nullptr, yroot, N, 256, 128);
    }
    agg_combine<<<nwb, TB, 0, stream>>>(yrel, yroot, rowp, srcs,
                                        b_rel1, bn_g1, bn_b1, bn_m1, bn_v1,
                                        aggb /*h1*/, N, 128);

    // ---- layer 2: same with 64 outputs; h2 overwrites h0 region
    {
        dim3 g((N + TS - 1) / TS, 64 / TS);
        gemm_bn<<<g, TB, 0, stream>>>(aggb, nullptr, W_rel2, nullptr, nullptr,
                                      nullptr, nullptr, nullptr, nullptr, yrel, N, 128, 64);
        gemm_bn<<<g, TB, 0, stream>>>(aggb, nullptr, W_root2, nullptr, nullptr,
                                      nullptr, nullptr, nullptr, nullptr, yroot, N, 128, 64);
    }
    float* h2 = h0;
    agg_combine<<<nwb, TB, 0, stream>>>(yrel, yroot, rowp, srcs,
                                        b_rel2, bn_g2, bn_b2, bn_m2, bn_v2,
                                        h2, N, 64);

    // ---- mean pool + head
    pool_kernel<<<((size_t)N * 64 + TB - 1) / TB, TB, 0, stream>>>(h2, batch, pooled, cntg, N);
    head_kernel<<<1, TB, 0, stream>>>(pooled, cntg, W_out, b_out, (float*)d_out);
}

// Round 2
// 787.823 us; speedup vs baseline: 1.4515x; 1.4515x over previous
//
#include <hip/hip_runtime.h>

// GeneticDosageGNN: 3x GraphConv(+BN+ReLU) -> mean pool -> linear head
// N=50000 nodes, E=800000 edges, dims 128->256->128->64->3, 64 graphs.

constexpr int TS = 64;   // GEMM tile (rows=nodes, cols=features)
constexpr int BKK = 32;  // GEMM K-tile

// ---------------- CSR build ----------------

__global__ __launch_bounds__(256)
void hist_kernel(const int* __restrict__ dst, int* __restrict__ cnt, int E) {
    int i = blockIdx.x * blockDim.x + threadIdx.x;
    if (i < E) atomicAdd(&cnt[dst[i]], 1);
}

__global__ void scan_kernel(const int* __restrict__ cnt, int* __restrict__ rowptr,
                            int* __restrict__ pos, int N) {
    __shared__ int sums[1024];
    int t = threadIdx.x;
    int chunk = (N + 1023) / 1024;
    int b = t * chunk;
    int e = min(b + chunk, N);
    int s = 0;
    for (int i = b; i < e; ++i) s += cnt[i];
    sums[t] = s;
    __syncthreads();
    for (int d = 1; d < 1024; d <<= 1) {
        int val = (t >= d) ? sums[t - d] : 0;
        __syncthreads();
        sums[t] += val;
        __syncthreads();
    }
    int run = (t == 0) ? 0 : sums[t - 1];
    for (int i = b; i < e; ++i) {
        rowptr[i] = run;
        pos[i] = run;
        run += cnt[i];
    }
    if (t == 1023) rowptr[N] = run;
}

__global__ __launch_bounds__(256)
void scatter_kernel(const int* __restrict__ src, const int* __restrict__ dst,
                    int* __restrict__ pos, int* __restrict__ srcs, int E) {
    int i = blockIdx.x * blockDim.x + threadIdx.x;
    if (i < E) {
        int p = atomicAdd(&pos[dst[i]], 1);
        srcs[p] = src[i];
    }
}

// ---------------- aggregation (+optional root/bias/BN/ReLU) ----------------
// One 64-lane wave per node. F = 64 or 128 features.

__global__ __launch_bounds__(256)
void agg_combine(const float* __restrict__ ysrc,   // [N,F] gathered over edges
                 const float* __restrict__ yroot,  // nullable [N,F]
                 const int* __restrict__ rowptr,
                 const int* __restrict__ srcs,
                 const float* __restrict__ bias,   // nullable [F]
                 const float* __restrict__ bng, const float* __restrict__ bnb,
                 const float* __restrict__ bnm, const float* __restrict__ bnv,
                 float* __restrict__ out, int N, int F)
{
    int w = (blockIdx.x * blockDim.x + threadIdx.x) >> 6;
    int lane = threadIdx.x & 63;
    if (w >= N) return;
    int beg = rowptr[w], end = rowptr[w + 1];
    float acc0 = 0.f, acc1 = 0.f;
    for (int e = beg; e < end; ++e) {
        int s = srcs[e];
        const float* p = ysrc + (size_t)s * F;
        acc0 += p[lane];
        if (F == 128) acc1 += p[64 + lane];
    }
#pragma unroll
    for (int h = 0; h < 2; ++h) {
        if (h == 1 && F == 64) break;
        int f = lane + h * 64;
        float val = (h == 0) ? acc0 : acc1;
        if (yroot) val += yroot[(size_t)w * F + f];
        if (bias) val += bias[f];
        if (bng) {
            val = (val - bnm[f]) * rsqrtf(bnv[f] + 1e-5f) * bng[f] + bnb[f];
            val = fmaxf(val, 0.f);
        }
        out[(size_t)w * F + f] = val;
    }
}

// ---------------- fused GEMM: C = act(A1@W1 [+ A2@W2] [+bias] [BN+ReLU]) ----

__global__ __launch_bounds__(256)
void gemm_bn(const float* __restrict__ A1, const float* __restrict__ A2,
             const float* __restrict__ W1, const float* __restrict__ W2,
             const float* __restrict__ bias,
             const float* __restrict__ bng, const float* __restrict__ bnb,
             const float* __restrict__ bnm, const float* __restrict__ bnv,
             float* __restrict__ C, int N, int K, int M)
{
    __shared__ float As[BKK][TS];
    __shared__ float Ws[BKK][TS];
    const int n0 = blockIdx.x * TS;
    const int m0 = blockIdx.y * TS;
    const int tid = threadIdx.x;
    const int tx = tid & 15, ty = tid >> 4;
    float acc[4][4] = {};
    const int nsrc = A2 ? 2 : 1;
    for (int s = 0; s < nsrc; ++s) {
        const float* __restrict__ A = s ? A2 : A1;
        const float* __restrict__ W = s ? W2 : W1;
        for (int k0 = 0; k0 < K; k0 += BKK) {
            __syncthreads();
            // A tile: 64 rows x 32 k, stored transposed As[k][row]
#pragma unroll
            for (int p = 0; p < 2; ++p) {
                int row = (tid >> 3) + p * 32;
                int kq = (tid & 7) * 4;
                int n = n0 + row;
                float4 a = make_float4(0.f, 0.f, 0.f, 0.f);
                if (n < N) a = *(const float4*)(A + (size_t)n * K + k0 + kq);
                As[kq + 0][row] = a.x;
                As[kq + 1][row] = a.y;
                As[kq + 2][row] = a.z;
                As[kq + 3][row] = a.w;
            }
            // W tile: 32 k x 64 cols
#pragma unroll
            for (int p = 0; p < 2; ++p) {
                int k = (tid >> 4) + p * 16;
                int mq = (tid & 15) * 4;
                *(float4*)&Ws[k][mq] = *(const float4*)(W + (size_t)(k0 + k) * M + m0 + mq);
            }
            __syncthreads();
#pragma unroll
            for (int k = 0; k < BKK; ++k) {
                float4 a = *(const float4*)&As[k][ty * 4];
                float4 w = *(const float4*)&Ws[k][tx * 4];
                float av[4] = {a.x, a.y, a.z, a.w};
                float wv[4] = {w.x, w.y, w.z, w.w};
#pragma unroll
                for (int i = 0; i < 4; ++i)
#pragma unroll
                    for (int j = 0; j < 4; ++j)
                        acc[i][j] = fmaf(av[i], wv[j], acc[i][j]);
            }
        }
    }
#pragma unroll
    for (int i = 0; i < 4; ++i) {
        int n = n0 + ty * 4 + i;
        if (n >= N) continue;
#pragma unroll
        for (int j = 0; j < 4; ++j) {
            int mm = m0 + tx * 4 + j;
            float val = acc[i][j];
            if (bias) val += bias[mm];
            if (bng) {
                val = (val - bnm[mm]) * rsqrtf(bnv[mm] + 1e-5f) * bng[mm] + bnb[mm];
                val = fmaxf(val, 0.f);
            }
            C[(size_t)n * M + mm] = val;
        }
    }
}

// ---------------- pooling + head (batch is sorted -> contiguous ranges) ----

__global__ void bounds_kernel(const int* __restrict__ batch, int* __restrict__ start, int N) {
    int g = threadIdx.x;
    if (g > 64) return;
    int lo = 0, hi = N;
    while (lo < hi) {
        int mid = (lo + hi) >> 1;
        if (batch[mid] < g) lo = mid + 1; else hi = mid;
    }
    start[g] = lo;
}

// One block per graph: mean over its node range, then 3-wide head dot.
__global__ __launch_bounds__(256)
void pool_head_kernel(const float* __restrict__ h, const int* __restrict__ start,
                      const float* __restrict__ Wout, const float* __restrict__ bout,
                      float* __restrict__ out) {
    int g = blockIdx.x;
    int f = threadIdx.x & 63, sub = threadIdx.x >> 6;
    int beg = start[g], end = start[g + 1];
    float acc = 0.f;
    for (int n = beg + sub; n < end; n += 4)
        acc += h[(size_t)n * 64 + f];
    __shared__ float red[4][64];
    red[sub][f] = acc;
    __syncthreads();
    if (sub == 0) {
        float v = red[0][f] + red[1][f] + red[2][f] + red[3][f];
        float cnt = fmaxf((float)(end - beg), 1.0f);
        red[0][f] = v / cnt;
    }
    __syncthreads();
    if (threadIdx.x < 3) {
        int o = threadIdx.x;
        float s = 0.f;
#pragma unroll
        for (int k = 0; k < 64; ++k) s += red[0][k] * Wout[k * 3 + o];
        out[g * 3 + o] = s + bout[o];
    }
}

// ---------------- launch ----------------

extern "C" void kernel_launch(void* const* d_in, const int* in_sizes, int n_in,
                              void* d_out, int out_size, void* d_ws, size_t ws_size,
                              hipStream_t stream)
{
    const float* x       = (const float*)d_in[0];
    const int*   ei      = (const int*)d_in[1];
    const int*   batch   = (const int*)d_in[2];
    const float* W_rel0  = (const float*)d_in[3];
    const float* b_rel0  = (const float*)d_in[4];
    const float* W_root0 = (const float*)d_in[5];
    const float* bn_g0   = (const float*)d_in[6];
    const float* bn_b0   = (const float*)d_in[7];
    const float* bn_m0   = (const float*)d_in[8];
    const float* bn_v0   = (const float*)d_in[9];
    const float* W_rel1  = (const float*)d_in[10];
    const float* b_rel1  = (const float*)d_in[11];
    const float* W_root1 = (const float*)d_in[12];
    const float* bn_g1   = (const float*)d_in[13];
    const float* bn_b1   = (const float*)d_in[14];
    const float* bn_m1   = (const float*)d_in[15];
    const float* bn_v1   = (const float*)d_in[16];
    const float* W_rel2  = (const float*)d_in[17];
    const float* b_rel2  = (const float*)d_in[18];
    const float* W_root2 = (const float*)d_in[19];
    const float* bn_g2   = (const float*)d_in[20];
    const float* bn_b2   = (const float*)d_in[21];
    const float* bn_m2   = (const float*)d_in[22];
    const float* bn_v2   = (const float*)d_in[23];
    const float* W_out   = (const float*)d_in[24];
    const float* b_out   = (const float*)d_in[25];

    const int N = in_sizes[0] / 128;
    const int E = in_sizes[1] / 2;
    const int* src = ei;
    const int* dst = ei + E;

    char* ws = (char*)d_ws;
    size_t off = 0;
    auto alloc = [&](size_t b) -> void* {
        off = (off + 255) & ~(size_t)255;
        void* p = ws + off;
        off += b;
        return p;
    };

    float* h0    = (float*)alloc((size_t)N * 256 * 4);  // layer0 out; reused as h2 [N,64]
    float* yrel  = (float*)alloc((size_t)N * 128 * 4);  // rel-GEMM out (L1: [N,128], L2: [N,64])
    float* yroot = (float*)alloc((size_t)N * 128 * 4);  // root-GEMM out
    float* aggb  = (float*)alloc((size_t)N * 128 * 4);  // agg0 in L0; h1 [N,128] in L1
    int*   cnt   = (int*)alloc((size_t)N * 4);
    int*   rowp  = (int*)alloc((size_t)(N + 1) * 4);
    int*   pos   = (int*)alloc((size_t)N * 4);
    int*   srcs  = (int*)alloc((size_t)E * 4);
    int*   gstart = (int*)alloc(65 * 4);

    hipMemsetAsync(cnt, 0, (size_t)N * 4, stream);

    const int TB = 256;
    const int egrid = (E + TB - 1) / TB;
    const int nwb = (N + 3) / 4;  // 4 waves (nodes) per 256-thread block

    hist_kernel<<<egrid, TB, 0, stream>>>(dst, cnt, E);
    scan_kernel<<<1, 1024, 0, stream>>>(cnt, rowp, pos, N);
    scatter_kernel<<<egrid, TB, 0, stream>>>(src, dst, pos, srcs, E);
    bounds_kernel<<<1, 128, 0, stream>>>(batch, gstart, N);

    // ---- layer 0: agg x (128) first, then [agg|x] @ [Wrel;Wroot] + b, BN, ReLU
    agg_combine<<<nwb, TB, 0, stream>>>(x, nullptr, rowp, srcs,
                                        nullptr, nullptr, nullptr, nullptr, nullptr,
                                        aggb, N, 128);
    {
        dim3 g((N + TS - 1) / TS, 256 / TS);
        gemm_bn<<<g, TB, 0, stream>>>(aggb, x, W_rel0, W_root0, b_rel0,
                                      bn_g0, bn_b0, bn_m0, bn_v0, h0, N, 128, 256);
    }

    // ---- layer 1: yrel/yroot = h0 @ Wrel1/Wroot1, then agg(yrel)+yroot+b, BN, ReLU
    {
        dim3 g((N + TS - 1) / TS, 128 / TS);
        gemm_bn<<<g, TB, 0, stream>>>(h0, nullptr, W_rel1, nullptr, nullptr,
                                      nullptr, nullptr, nullptr, nullptr, yrel, N, 256, 128);
        gemm_bn<<<g, TB, 0, stream>>>(h0, nullptr, W_root1, nullptr, nullptr,
                                      nullptr, nullptr, nullptr, nullptr, yroot, N, 256, 128);
    }
    agg_combine<<<nwb, TB, 0, stream>>>(yrel, yroot, rowp, srcs,
                                        b_rel1, bn_g1, bn_b1, bn_m1, bn_v1,
                                        aggb /*h1*/, N, 128);

    // ---- layer 2: same with 64 outputs; h2 overwrites h0 region
    {
        dim3 g((N + TS - 1) / TS, 64 / TS);
        gemm_bn<<<g, TB, 0, stream>>>(aggb, nullptr, W_rel2, nullptr, nullptr,
                                      nullptr, nullptr, nullptr, nullptr, yrel, N, 128, 64);
        gemm_bn<<<g, TB, 0, stream>>>(aggb, nullptr, W_root2, nullptr, nullptr,
                                      nullptr, nullptr, nullptr, nullptr, yroot, N, 128, 64);
    }
    float* h2 = h0;
    agg_combine<<<nwb, TB, 0, stream>>>(yrel, yroot, rowp, srcs,
                                        b_rel2, bn_g2, bn_b2, bn_m2, bn_v2,
                                        h2, N, 64);

    // ---- mean pool + head (no atomics; batch is sorted)
    pool_head_kernel<<<64, TB, 0, stream>>>(h2, gstart, W_out, b_out, (float*)d_out);
}

// Round 3
// 506.486 us; speedup vs baseline: 2.2578x; 1.5555x over previous
//
#include <hip/hip_runtime.h>

// GeneticDosageGNN: 3x GraphConv(+BN+ReLU) -> mean pool -> linear head
// N=50000 nodes, E=800000 edges, dims 128->256->128->64->3, 64 graphs.
// R3: bf16 MFMA GEMMs (fused rel|root), bf16 intermediates for gathers.

typedef __attribute__((ext_vector_type(8))) short    bf16x8;
typedef __attribute__((ext_vector_type(4))) float    f32x4;
typedef __attribute__((ext_vector_type(8))) unsigned short ush8;
typedef __attribute__((ext_vector_type(4))) unsigned short ush4;

__device__ __forceinline__ unsigned short f2b(float f) {
    union { float f; unsigned int u; } c; c.f = f;
    unsigned int u = c.u;
    return (unsigned short)((u + 0x7fffu + ((u >> 16) & 1u)) >> 16);
}
__device__ __forceinline__ float b2f(unsigned short h) {
    union { unsigned int u; float f; } c; c.u = ((unsigned int)h) << 16;
    return c.f;
}

// ---------------- CSR build ----------------

__global__ __launch_bounds__(256)
void hist_kernel(const int* __restrict__ dst, int* __restrict__ cnt, int E) {
    int i = blockIdx.x * blockDim.x + threadIdx.x;
    if (i < E) atomicAdd(&cnt[dst[i]], 1);
}

__global__ void scan_kernel(const int* __restrict__ cnt, int* __restrict__ rowptr,
                            int* __restrict__ pos, int N) {
    __shared__ int sums[1024];
    int t = threadIdx.x;
    int chunk = (N + 1023) / 1024;
    int b = t * chunk;
    int e = min(b + chunk, N);
    int s = 0;
    for (int i = b; i < e; ++i) s += cnt[i];
    sums[t] = s;
    __syncthreads();
    for (int d = 1; d < 1024; d <<= 1) {
        int val = (t >= d) ? sums[t - d] : 0;
        __syncthreads();
        sums[t] += val;
        __syncthreads();
    }
    int run = (t == 0) ? 0 : sums[t - 1];
    for (int i = b; i < e; ++i) {
        rowptr[i] = run;
        pos[i] = run;
        run += cnt[i];
    }
    if (t == 1023) rowptr[N] = run;
}

__global__ __launch_bounds__(256)
void scatter_kernel(const int* __restrict__ src, const int* __restrict__ dst,
                    int* __restrict__ pos, int* __restrict__ srcs, int E) {
    int i = blockIdx.x * blockDim.x + threadIdx.x;
    if (i < E) {
        int p = atomicAdd(&pos[dst[i]], 1);
        srcs[p] = src[i];
    }
}

__global__ void bounds_kernel(const int* __restrict__ batch, int* __restrict__ start, int N) {
    int g = threadIdx.x;
    if (g > 64) return;
    int lo = 0, hi = N;
    while (lo < hi) {
        int mid = (lo + hi) >> 1;
        if (batch[mid] < g) lo = mid + 1; else hi = mid;
    }
    start[g] = lo;
}

// ---------------- conversions ----------------

__global__ __launch_bounds__(256)
void conv_x_kernel(const float* __restrict__ x, unsigned short* __restrict__ xb, int n4) {
    int i = blockIdx.x * 256 + threadIdx.x;
    if (i >= n4) return;
    float4 v = ((const float4*)x)[i];
    ush4 o = { f2b(v.x), f2b(v.y), f2b(v.z), f2b(v.w) };
    *(ush4*)(xb + (size_t)i * 4) = o;
}

// Build transposed bf16 weight buffers:
//  Wt0  [256][256]: row m, k<128 -> Wrel0[k][m], k>=128 -> Wroot0[k-128][m]
//  WtC1 [256][256]: row m<128 -> Wrel1[k][m], m>=128 -> Wroot1[k][m-128]
//  WtC2 [128][128]: row m<64  -> Wrel2[k][m], m>=64  -> Wroot2[k][m-64]
__global__ __launch_bounds__(256)
void conv_weights_kernel(const float* __restrict__ Wrel0, const float* __restrict__ Wroot0,
                         const float* __restrict__ Wrel1, const float* __restrict__ Wroot1,
                         const float* __restrict__ Wrel2, const float* __restrict__ Wroot2,
                         unsigned short* __restrict__ Wt0,
                         unsigned short* __restrict__ WtC1,
                         unsigned short* __restrict__ WtC2) {
    int i = blockIdx.x * 256 + threadIdx.x;
    if (i < 65536) {
        int m = i >> 8, k = i & 255;
        float v = (k < 128) ? Wrel0[k * 256 + m] : Wroot0[(k - 128) * 256 + m];
        Wt0[i] = f2b(v);
    } else if (i < 131072) {
        int j = i - 65536;
        int m = j >> 8, k = j & 255;
        float v = (m < 128) ? Wrel1[k * 128 + m] : Wroot1[k * 128 + (m - 128)];
        WtC1[j] = f2b(v);
    } else if (i < 147456) {
        int j = i - 131072;
        int m = j >> 7, k = j & 127;
        float v = (m < 64) ? Wrel2[k * 64 + m] : Wroot2[k * 64 + (m - 64)];
        WtC2[j] = f2b(v);
    }
}

// ---------------- aggregation over CSR (+root/bias/BN/ReLU), bf16 ----------

template<int F>
__global__ __launch_bounds__(256)
void agg_bf16(const unsigned short* __restrict__ ysrc, int ystride,
              const unsigned short* __restrict__ yroot, int rstride,
              const int* __restrict__ rowptr, const int* __restrict__ srcs,
              const float* __restrict__ bias,
              const float* __restrict__ bng, const float* __restrict__ bnb,
              const float* __restrict__ bnm, const float* __restrict__ bnv,
              unsigned short* __restrict__ out, int N)
{
    int w = (blockIdx.x * blockDim.x + threadIdx.x) >> 6;
    int lane = threadIdx.x & 63;
    if (w >= N) return;
    int beg = rowptr[w], end = rowptr[w + 1];
    float a0 = 0.f, a1 = 0.f;
    if (F == 128) {
        int e = beg;
        for (; e + 1 < end; e += 2) {
            int s0 = srcs[e], s1 = srcs[e + 1];
            unsigned int u0 = *(const unsigned int*)(ysrc + (size_t)s0 * ystride + lane * 2);
            unsigned int u1 = *(const unsigned int*)(ysrc + (size_t)s1 * ystride + lane * 2);
            a0 += b2f((unsigned short)(u0 & 0xffff)) + b2f((unsigned short)(u1 & 0xffff));
            a1 += b2f((unsigned short)(u0 >> 16)) + b2f((unsigned short)(u1 >> 16));
        }
        if (e < end) {
            unsigned int u = *(const unsigned int*)(ysrc + (size_t)srcs[e] * ystride + lane * 2);
            a0 += b2f((unsigned short)(u & 0xffff));
            a1 += b2f((unsigned short)(u >> 16));
        }
        int f0 = lane * 2, f1 = lane * 2 + 1;
        if (yroot) {
            unsigned int u = *(const unsigned int*)(yroot + (size_t)w * rstride + lane * 2);
            a0 += b2f((unsigned short)(u & 0xffff));
            a1 += b2f((unsigned short)(u >> 16));
        }
        if (bias) {
            a0 += bias[f0]; a1 += bias[f1];
            a0 = (a0 - bnm[f0]) * rsqrtf(bnv[f0] + 1e-5f) * bng[f0] + bnb[f0];
            a1 = (a1 - bnm[f1]) * rsqrtf(bnv[f1] + 1e-5f) * bng[f1] + bnb[f1];
            a0 = fmaxf(a0, 0.f); a1 = fmaxf(a1, 0.f);
        }
        unsigned int o = (unsigned int)f2b(a0) | ((unsigned int)f2b(a1) << 16);
        *(unsigned int*)(out + (size_t)w * 128 + lane * 2) = o;
    } else {  // F == 64
        int e = beg;
        for (; e + 1 < end; e += 2) {
            int s0 = srcs[e], s1 = srcs[e + 1];
            a0 += b2f(ysrc[(size_t)s0 * ystride + lane]) + b2f(ysrc[(size_t)s1 * ystride + lane]);
        }
        if (e < end) a0 += b2f(ysrc[(size_t)srcs[e] * ystride + lane]);
        int f = lane;
        if (yroot) a0 += b2f(yroot[(size_t)w * rstride + lane]);
        if (bias) {
            a0 += bias[f];
            a0 = (a0 - bnm[f]) * rsqrtf(bnv[f] + 1e-5f) * bng[f] + bnb[f];
            a0 = fmaxf(a0, 0.f);
        }
        out[(size_t)w * 64 + lane] = f2b(a0);
    }
}

// ---------------- bf16 MFMA GEMM: C = [epi](A @ Wt^T) -----------------------
// A: [N, Ktot] bf16 (optionally split: k<128 from A1, k>=128 from A2, each [N,128])
// Wt: [M][Ktot] bf16 (row m = output column m). C: [N, M] bf16.
// Tile: BM=128, BN=128, BK=64; 4 waves, each 64x64 (4x4 frags of 16x16x32).

__global__ __launch_bounds__(256)
void gemm_mfma(const unsigned short* __restrict__ A1,
               const unsigned short* __restrict__ A2,
               const unsigned short* __restrict__ Wt,
               const float* __restrict__ bias,
               const float* __restrict__ bng, const float* __restrict__ bnb,
               const float* __restrict__ bnm, const float* __restrict__ bnv,
               unsigned short* __restrict__ C, int N, int Ktot, int M)
{
    __shared__ unsigned short As[128][64];
    __shared__ unsigned short Ws[128][64];

    const int tid = threadIdx.x;
    const int n0 = blockIdx.x * 128;
    const int m0 = blockIdx.y * 128;
    const int wid = tid >> 6, lane = tid & 63;
    const int wm = wid >> 1, wn = wid & 1;
    const int lr = lane & 15, lg = lane >> 4;
    const int strideA = A2 ? 128 : Ktot;

    f32x4 acc[4][4] = {};

    for (int k0 = 0; k0 < Ktot; k0 += 64) {
        // stage A tile [128][64] and Wt tile [128][64]
#pragma unroll
        for (int it = 0; it < 4; ++it) {
            int c = tid + it * 256;          // 0..1023
            int row = c >> 3;
            int kb = (c & 7) << 3;           // 0..56, step 8
            int sw = kb ^ ((row & 7) << 3);
            // A
            int n = n0 + row;
            int ksrc = k0 + kb;
            const unsigned short* Ap = A1; int kl = ksrc;
            if (A2 && ksrc >= 128) { Ap = A2; kl = ksrc - 128; }
            ush8 va = {};
            if (n < N) va = *(const ush8*)(Ap + (size_t)n * strideA + kl);
            *(ush8*)&As[row][sw] = va;
            // Wt
            ush8 vw = *(const ush8*)(Wt + (size_t)(m0 + row) * Ktot + k0 + kb);
            *(ush8*)&Ws[row][sw] = vw;
        }
        __syncthreads();
#pragma unroll
        for (int s = 0; s < 2; ++s) {
            int kk = s * 32 + lg * 8;
            bf16x8 af[4], bfr[4];
#pragma unroll
            for (int i = 0; i < 4; ++i) {
                int row = wm * 64 + i * 16 + lr;
                af[i] = *(const bf16x8*)&As[row][kk ^ ((row & 7) << 3)];
            }
#pragma unroll
            for (int j = 0; j < 4; ++j) {
                int n = wn * 64 + j * 16 + lr;
                bfr[j] = *(const bf16x8*)&Ws[n][kk ^ ((n & 7) << 3)];
            }
#pragma unroll
            for (int i = 0; i < 4; ++i)
#pragma unroll
                for (int j = 0; j < 4; ++j)
                    acc[i][j] = __builtin_amdgcn_mfma_f32_16x16x32_bf16(af[i], bfr[j], acc[i][j], 0, 0, 0);
        }
        __syncthreads();
    }

    // epilogue: D row=(lg*4+r), col=lr within each 16x16 frag
#pragma unroll
    for (int i = 0; i < 4; ++i) {
#pragma unroll
        for (int r = 0; r < 4; ++r) {
            int row = n0 + wm * 64 + i * 16 + lg * 4 + r;
            if (row >= N) continue;
#pragma unroll
            for (int j = 0; j < 4; ++j) {
                int col = m0 + wn * 64 + j * 16 + lr;
                float val = acc[i][j][r];
                if (bias) {
                    val += bias[col];
                    val = (val - bnm[col]) * rsqrtf(bnv[col] + 1e-5f) * bng[col] + bnb[col];
                    val = fmaxf(val, 0.f);
                }
                C[(size_t)row * M + col] = f2b(val);
            }
        }
    }
}

// ---------------- pooling + head (bf16 h, batch sorted) ---------------------

__global__ __launch_bounds__(256)
void pool_head_kernel(const unsigned short* __restrict__ h, const int* __restrict__ start,
                      const float* __restrict__ Wout, const float* __restrict__ bout,
                      float* __restrict__ out) {
    int g = blockIdx.x;
    int f = threadIdx.x & 63, sub = threadIdx.x >> 6;
    int beg = start[g], end = start[g + 1];
    float acc = 0.f;
    for (int n = beg + sub; n < end; n += 4)
        acc += b2f(h[(size_t)n * 64 + f]);
    __shared__ float red[4][64];
    red[sub][f] = acc;
    __syncthreads();
    if (sub == 0) {
        float v = red[0][f] + red[1][f] + red[2][f] + red[3][f];
        float cnt = fmaxf((float)(end - beg), 1.0f);
        red[0][f] = v / cnt;
    }
    __syncthreads();
    if (threadIdx.x < 3) {
        int o = threadIdx.x;
        float s = 0.f;
#pragma unroll
        for (int k = 0; k < 64; ++k) s += red[0][k] * Wout[k * 3 + o];
        out[g * 3 + o] = s + bout[o];
    }
}

// ---------------- launch ----------------------------------------------------

extern "C" void kernel_launch(void* const* d_in, const int* in_sizes, int n_in,
                              void* d_out, int out_size, void* d_ws, size_t ws_size,
                              hipStream_t stream)
{
    const float* x       = (const float*)d_in[0];
    const int*   ei      = (const int*)d_in[1];
    const int*   batch   = (const int*)d_in[2];
    const float* W_rel0  = (const float*)d_in[3];
    const float* b_rel0  = (const float*)d_in[4];
    const float* W_root0 = (const float*)d_in[5];
    const float* bn_g0   = (const float*)d_in[6];
    const float* bn_b0   = (const float*)d_in[7];
    const float* bn_m0   = (const float*)d_in[8];
    const float* bn_v0   = (const float*)d_in[9];
    const float* W_rel1  = (const float*)d_in[10];
    const float* b_rel1  = (const float*)d_in[11];
    const float* W_root1 = (const float*)d_in[12];
    const float* bn_g1   = (const float*)d_in[13];
    const float* bn_b1   = (const float*)d_in[14];
    const float* bn_m1   = (const float*)d_in[15];
    const float* bn_v1   = (const float*)d_in[16];
    const float* W_rel2  = (const float*)d_in[17];
    const float* b_rel2  = (const float*)d_in[18];
    const float* W_root2 = (const float*)d_in[19];
    const float* bn_g2   = (const float*)d_in[20];
    const float* bn_b2   = (const float*)d_in[21];
    const float* bn_m2   = (const float*)d_in[22];
    const float* bn_v2   = (const float*)d_in[23];
    const float* W_out   = (const float*)d_in[24];
    const float* b_out   = (const float*)d_in[25];

    const int N = in_sizes[0] / 128;
    const int E = in_sizes[1] / 2;
    const int* src = ei;
    const int* dst = ei + E;

    char* ws = (char*)d_ws;
    size_t off = 0;
    auto alloc = [&](size_t b) -> void* {
        off = (off + 255) & ~(size_t)255;
        void* p = ws + off;
        off += b;
        return p;
    };

    unsigned short* xb16   = (unsigned short*)alloc((size_t)N * 128 * 2);
    unsigned short* aggb16 = (unsigned short*)alloc((size_t)N * 128 * 2);
    unsigned short* h0     = (unsigned short*)alloc((size_t)N * 256 * 2);
    unsigned short* ycomb1 = (unsigned short*)alloc((size_t)N * 256 * 2);
    unsigned short* h1     = (unsigned short*)alloc((size_t)N * 128 * 2);
    unsigned short* ycomb2 = (unsigned short*)alloc((size_t)N * 128 * 2);
    unsigned short* h2     = (unsigned short*)alloc((size_t)N * 64 * 2);
    unsigned short* Wt0    = (unsigned short*)alloc(256 * 256 * 2);
    unsigned short* WtC1   = (unsigned short*)alloc(256 * 256 * 2);
    unsigned short* WtC2   = (unsigned short*)alloc(128 * 128 * 2);
    int* cnt    = (int*)alloc((size_t)N * 4);
    int* rowp   = (int*)alloc((size_t)(N + 1) * 4);
    int* pos    = (int*)alloc((size_t)N * 4);
    int* srcs   = (int*)alloc((size_t)E * 4);
    int* gstart = (int*)alloc(65 * 4);

    hipMemsetAsync(cnt, 0, (size_t)N * 4, stream);

    const int TB = 256;
    const int egrid = (E + TB - 1) / TB;
    const int nwb = (N + 3) / 4;

    hist_kernel<<<egrid, TB, 0, stream>>>(dst, cnt, E);
    scan_kernel<<<1, 1024, 0, stream>>>(cnt, rowp, pos, N);
    scatter_kernel<<<egrid, TB, 0, stream>>>(src, dst, pos, srcs, E);
    bounds_kernel<<<1, 128, 0, stream>>>(batch, gstart, N);

    conv_weights_kernel<<<576, TB, 0, stream>>>(W_rel0, W_root0, W_rel1, W_root1,
                                                W_rel2, W_root2, Wt0, WtC1, WtC2);
    conv_x_kernel<<<(N * 128 / 4 + TB - 1) / TB, TB, 0, stream>>>(x, xb16, N * 128 / 4);

    const int gx = (N + 127) / 128;

    // layer 0: agg(x) -> [agg|x] @ Wt0 (+bias,BN,ReLU) -> h0 [N,256]
    agg_bf16<128><<<nwb, TB, 0, stream>>>(xb16, 128, nullptr, 0, rowp, srcs,
                                          nullptr, nullptr, nullptr, nullptr, nullptr,
                                          aggb16, N);
    gemm_mfma<<<dim3(gx, 2), TB, 0, stream>>>(aggb16, xb16, Wt0,
                                              b_rel0, bn_g0, bn_b0, bn_m0, bn_v0,
                                              h0, N, 256, 256);

    // layer 1: ycomb1 = h0 @ [Wrel1|Wroot1]; h1 = bnrelu(agg(yrel)+yroot+b)
    gemm_mfma<<<dim3(gx, 2), TB, 0, stream>>>(h0, nullptr, WtC1,
                                              nullptr, nullptr, nullptr, nullptr, nullptr,
                                              ycomb1, N, 256, 256);
    agg_bf16<128><<<nwb, TB, 0, stream>>>(ycomb1, 256, ycomb1 + 128, 256, rowp, srcs,
                                          b_rel1, bn_g1, bn_b1, bn_m1, bn_v1,
                                          h1, N);

    // layer 2: ycomb2 = h1 @ [Wrel2|Wroot2]; h2 = bnrelu(agg(yrel)+yroot+b)
    gemm_mfma<<<dim3(gx, 1), TB, 0, stream>>>(h1, nullptr, WtC2,
                                              nullptr, nullptr, nullptr, nullptr, nullptr,
                                              ycomb2, N, 128, 128);
    agg_bf16<64><<<nwb, TB, 0, stream>>>(ycomb2, 128, ycomb2 + 64, 128, rowp, srcs,
                                         b_rel2, bn_g2, bn_b2, bn_m2, bn_v2,
                                         h2, N);

    // mean pool + head
    pool_head_kernel<<<64, TB, 0, stream>>>(h2, gstart, W_out, b_out, (float*)d_out);
}

// Round 4
// 402.609 us; speedup vs baseline: 2.8403x; 1.2580x over previous
//
#include <hip/hip_runtime.h>

// GeneticDosageGNN: 3x GraphConv(+BN+ReLU) -> mean pool -> linear head
// N=50000 nodes, E=800000 edges, dims 128->256->128->64->3, 64 graphs.
// R4: multi-block CSR scan (was 110us single-block -> ~5us).

typedef __attribute__((ext_vector_type(8))) short    bf16x8;
typedef __attribute__((ext_vector_type(4))) float    f32x4;
typedef __attribute__((ext_vector_type(8))) unsigned short ush8;
typedef __attribute__((ext_vector_type(4))) unsigned short ush4;

__device__ __forceinline__ unsigned short f2b(float f) {
    union { float f; unsigned int u; } c; c.f = f;
    unsigned int u = c.u;
    return (unsigned short)((u + 0x7fffu + ((u >> 16) & 1u)) >> 16);
}
__device__ __forceinline__ float b2f(unsigned short h) {
    union { unsigned int u; float f; } c; c.u = ((unsigned int)h) << 16;
    return c.f;
}

// ---------------- CSR build ----------------

__global__ __launch_bounds__(256)
void hist_kernel(const int* __restrict__ dst, int* __restrict__ cnt, int E) {
    int i = blockIdx.x * blockDim.x + threadIdx.x;
    if (i < E) atomicAdd(&cnt[dst[i]], 1);
}

// scan phase 1: per-block (1024 counts) reduction
__global__ __launch_bounds__(256)
void scan1_kernel(const int* __restrict__ cnt, int* __restrict__ bsum, int N) {
    __shared__ int red[256];
    int base = blockIdx.x * 1024;
    int t = threadIdx.x;
    int s = 0;
#pragma unroll
    for (int j = 0; j < 4; ++j) {
        int i = base + t * 4 + j;
        if (i < N) s += cnt[i];
    }
    red[t] = s;
    __syncthreads();
    for (int d = 128; d > 0; d >>= 1) {
        if (t < d) red[t] += red[t + d];
        __syncthreads();
    }
    if (t == 0) bsum[blockIdx.x] = red[0];
}

// scan phase 2: exclusive scan of block partials (nb <= 1024, tiny)
__global__ void scan2_kernel(const int* __restrict__ bsum, int* __restrict__ boff, int nb) {
    __shared__ int v[1024];
    int t = threadIdx.x;
    for (int i = t; i < nb; i += 256) v[i] = bsum[i];
    __syncthreads();
    if (t == 0) {
        int run = 0;
        for (int i = 0; i < nb; ++i) { int c = v[i]; v[i] = run; run += c; }
    }
    __syncthreads();
    for (int i = t; i < nb; i += 256) boff[i] = v[i];
}

// scan phase 3: in-block scan + offset, write rowptr & pos
__global__ __launch_bounds__(256)
void scan3_kernel(const int* __restrict__ cnt, const int* __restrict__ boff,
                  int* __restrict__ rowptr, int* __restrict__ pos, int N) {
    __shared__ int wsum[4];
    int base = blockIdx.x * 1024;
    int t = threadIdx.x;
    int lane = t & 63, wv = t >> 6;
    int c[4];
    int s = 0;
#pragma unroll
    for (int j = 0; j < 4; ++j) {
        int i = base + t * 4 + j;
        c[j] = (i < N) ? cnt[i] : 0;
        s += c[j];
    }
    int val = s;
#pragma unroll
    for (int d = 1; d < 64; d <<= 1) {
        int o = __shfl_up(val, d, 64);
        if (lane >= d) val += o;
    }
    if (lane == 63) wsum[wv] = val;
    __syncthreads();
    int wadd = 0;
    for (int i = 0; i < wv; ++i) wadd += wsum[i];
    int excl = val - s + wadd + boff[blockIdx.x];
#pragma unroll
    for (int j = 0; j < 4; ++j) {
        int i = base + t * 4 + j;
        if (i < N) {
            rowptr[i] = excl;
            pos[i] = excl;
            excl += c[j];
            if (i == N - 1) rowptr[N] = excl;
        }
    }
}

__global__ __launch_bounds__(256)
void scatter_kernel(const int* __restrict__ src, const int* __restrict__ dst,
                    int* __restrict__ pos, int* __restrict__ srcs, int E) {
    int i = blockIdx.x * blockDim.x + threadIdx.x;
    if (i < E) {
        int p = atomicAdd(&pos[dst[i]], 1);
        srcs[p] = src[i];
    }
}

__global__ void bounds_kernel(const int* __restrict__ batch, int* __restrict__ start, int N) {
    int g = threadIdx.x;
    if (g > 64) return;
    int lo = 0, hi = N;
    while (lo < hi) {
        int mid = (lo + hi) >> 1;
        if (batch[mid] < g) lo = mid + 1; else hi = mid;
    }
    start[g] = lo;
}

// ---------------- conversions ----------------

__global__ __launch_bounds__(256)
void conv_x_kernel(const float* __restrict__ x, unsigned short* __restrict__ xb, int n4) {
    int i = blockIdx.x * 256 + threadIdx.x;
    if (i >= n4) return;
    float4 v = ((const float4*)x)[i];
    ush4 o = { f2b(v.x), f2b(v.y), f2b(v.z), f2b(v.w) };
    *(ush4*)(xb + (size_t)i * 4) = o;
}

// Build transposed bf16 weight buffers:
//  Wt0  [256][256]: row m, k<128 -> Wrel0[k][m], k>=128 -> Wroot0[k-128][m]
//  WtC1 [256][256]: row m<128 -> Wrel1[k][m], m>=128 -> Wroot1[k][m-128]
//  WtC2 [128][128]: row m<64  -> Wrel2[k][m], m>=64  -> Wroot2[k][m-64]
__global__ __launch_bounds__(256)
void conv_weights_kernel(const float* __restrict__ Wrel0, const float* __restrict__ Wroot0,
                         const float* __restrict__ Wrel1, const float* __restrict__ Wroot1,
                         const float* __restrict__ Wrel2, const float* __restrict__ Wroot2,
                         unsigned short* __restrict__ Wt0,
                         unsigned short* __restrict__ WtC1,
                         unsigned short* __restrict__ WtC2) {
    int i = blockIdx.x * 256 + threadIdx.x;
    if (i < 65536) {
        int m = i >> 8, k = i & 255;
        float v = (k < 128) ? Wrel0[k * 256 + m] : Wroot0[(k - 128) * 256 + m];
        Wt0[i] = f2b(v);
    } else if (i < 131072) {
        int j = i - 65536;
        int m = j >> 8, k = j & 255;
        float v = (m < 128) ? Wrel1[k * 128 + m] : Wroot1[k * 128 + (m - 128)];
        WtC1[j] = f2b(v);
    } else if (i < 147456) {
        int j = i - 131072;
        int m = j >> 7, k = j & 127;
        float v = (m < 64) ? Wrel2[k * 64 + m] : Wroot2[k * 64 + (m - 64)];
        WtC2[j] = f2b(v);
    }
}

// ---------------- aggregation over CSR (+root/bias/BN/ReLU), bf16 ----------

template<int F>
__global__ __launch_bounds__(256)
void agg_bf16(const unsigned short* __restrict__ ysrc, int ystride,
              const unsigned short* __restrict__ yroot, int rstride,
              const int* __restrict__ rowptr, const int* __restrict__ srcs,
              const float* __restrict__ bias,
              const float* __restrict__ bng, const float* __restrict__ bnb,
              const float* __restrict__ bnm, const float* __restrict__ bnv,
              unsigned short* __restrict__ out, int N)
{
    int w = (blockIdx.x * blockDim.x + threadIdx.x) >> 6;
    int lane = threadIdx.x & 63;
    if (w >= N) return;
    int beg = rowptr[w], end = rowptr[w + 1];
    float a0 = 0.f, a1 = 0.f;
    if (F == 128) {
        int e = beg;
        for (; e + 1 < end; e += 2) {
            int s0 = srcs[e], s1 = srcs[e + 1];
            unsigned int u0 = *(const unsigned int*)(ysrc + (size_t)s0 * ystride + lane * 2);
            unsigned int u1 = *(const unsigned int*)(ysrc + (size_t)s1 * ystride + lane * 2);
            a0 += b2f((unsigned short)(u0 & 0xffff)) + b2f((unsigned short)(u1 & 0xffff));
            a1 += b2f((unsigned short)(u0 >> 16)) + b2f((unsigned short)(u1 >> 16));
        }
        if (e < end) {
            unsigned int u = *(const unsigned int*)(ysrc + (size_t)srcs[e] * ystride + lane * 2);
            a0 += b2f((unsigned short)(u & 0xffff));
            a1 += b2f((unsigned short)(u >> 16));
        }
        int f0 = lane * 2, f1 = lane * 2 + 1;
        if (yroot) {
            unsigned int u = *(const unsigned int*)(yroot + (size_t)w * rstride + lane * 2);
            a0 += b2f((unsigned short)(u & 0xffff));
            a1 += b2f((unsigned short)(u >> 16));
        }
        if (bias) {
            a0 += bias[f0]; a1 += bias[f1];
            a0 = (a0 - bnm[f0]) * rsqrtf(bnv[f0] + 1e-5f) * bng[f0] + bnb[f0];
            a1 = (a1 - bnm[f1]) * rsqrtf(bnv[f1] + 1e-5f) * bng[f1] + bnb[f1];
            a0 = fmaxf(a0, 0.f); a1 = fmaxf(a1, 0.f);
        }
        unsigned int o = (unsigned int)f2b(a0) | ((unsigned int)f2b(a1) << 16);
        *(unsigned int*)(out + (size_t)w * 128 + lane * 2) = o;
    } else {  // F == 64
        int e = beg;
        for (; e + 1 < end; e += 2) {
            int s0 = srcs[e], s1 = srcs[e + 1];
            a0 += b2f(ysrc[(size_t)s0 * ystride + lane]) + b2f(ysrc[(size_t)s1 * ystride + lane]);
        }
        if (e < end) a0 += b2f(ysrc[(size_t)srcs[e] * ystride + lane]);
        int f = lane;
        if (yroot) a0 += b2f(yroot[(size_t)w * rstride + lane]);
        if (bias) {
            a0 += bias[f];
            a0 = (a0 - bnm[f]) * rsqrtf(bnv[f] + 1e-5f) * bng[f] + bnb[f];
            a0 = fmaxf(a0, 0.f);
        }
        out[(size_t)w * 64 + lane] = f2b(a0);
    }
}

// ---------------- bf16 MFMA GEMM: C = [epi](A @ Wt^T) -----------------------
// A: [N, Ktot] bf16 (optionally split: k<128 from A1, k>=128 from A2, each [N,128])
// Wt: [M][Ktot] bf16 (row m = output column m). C: [N, M] bf16.
// Tile: BM=128, BN=128, BK=64; 4 waves, each 64x64 (4x4 frags of 16x16x32).

__global__ __launch_bounds__(256)
void gemm_mfma(const unsigned short* __restrict__ A1,
               const unsigned short* __restrict__ A2,
               const unsigned short* __restrict__ Wt,
               const float* __restrict__ bias,
               const float* __restrict__ bng, const float* __restrict__ bnb,
               const float* __restrict__ bnm, const float* __restrict__ bnv,
               unsigned short* __restrict__ C, int N, int Ktot, int M)
{
    __shared__ unsigned short As[128][64];
    __shared__ unsigned short Ws[128][64];

    const int tid = threadIdx.x;
    const int n0 = blockIdx.x * 128;
    const int m0 = blockIdx.y * 128;
    const int wid = tid >> 6, lane = tid & 63;
    const int wm = wid >> 1, wn = wid & 1;
    const int lr = lane & 15, lg = lane >> 4;
    const int strideA = A2 ? 128 : Ktot;

    f32x4 acc[4][4] = {};

    for (int k0 = 0; k0 < Ktot; k0 += 64) {
        // stage A tile [128][64] and Wt tile [128][64]
#pragma unroll
        for (int it = 0; it < 4; ++it) {
            int c = tid + it * 256;          // 0..1023
            int row = c >> 3;
            int kb = (c & 7) << 3;           // 0..56, step 8
            int sw = kb ^ ((row & 7) << 3);
            // A
            int n = n0 + row;
            int ksrc = k0 + kb;
            const unsigned short* Ap = A1; int kl = ksrc;
            if (A2 && ksrc >= 128) { Ap = A2; kl = ksrc - 128; }
            ush8 va = {};
            if (n < N) va = *(const ush8*)(Ap + (size_t)n * strideA + kl);
            *(ush8*)&As[row][sw] = va;
            // Wt
            ush8 vw = *(const ush8*)(Wt + (size_t)(m0 + row) * Ktot + k0 + kb);
            *(ush8*)&Ws[row][sw] = vw;
        }
        __syncthreads();
#pragma unroll
        for (int s = 0; s < 2; ++s) {
            int kk = s * 32 + lg * 8;
            bf16x8 af[4], bfr[4];
#pragma unroll
            for (int i = 0; i < 4; ++i) {
                int row = wm * 64 + i * 16 + lr;
                af[i] = *(const bf16x8*)&As[row][kk ^ ((row & 7) << 3)];
            }
#pragma unroll
            for (int j = 0; j < 4; ++j) {
                int n = wn * 64 + j * 16 + lr;
                bfr[j] = *(const bf16x8*)&Ws[n][kk ^ ((n & 7) << 3)];
            }
#pragma unroll
            for (int i = 0; i < 4; ++i)
#pragma unroll
                for (int j = 0; j < 4; ++j)
                    acc[i][j] = __builtin_amdgcn_mfma_f32_16x16x32_bf16(af[i], bfr[j], acc[i][j], 0, 0, 0);
        }
        __syncthreads();
    }

    // epilogue: D row=(lg*4+r), col=lr within each 16x16 frag
#pragma unroll
    for (int i = 0; i < 4; ++i) {
#pragma unroll
        for (int r = 0; r < 4; ++r) {
            int row = n0 + wm * 64 + i * 16 + lg * 4 + r;
            if (row >= N) continue;
#pragma unroll
            for (int j = 0; j < 4; ++j) {
                int col = m0 + wn * 64 + j * 16 + lr;
                float val = acc[i][j][r];
                if (bias) {
                    val += bias[col];
                    val = (val - bnm[col]) * rsqrtf(bnv[col] + 1e-5f) * bng[col] + bnb[col];
                    val = fmaxf(val, 0.f);
                }
                C[(size_t)row * M + col] = f2b(val);
            }
        }
    }
}

// ---------------- pooling + head (bf16 h, batch sorted) ---------------------

__global__ __launch_bounds__(256)
void pool_head_kernel(const unsigned short* __restrict__ h, const int* __restrict__ start,
                      const float* __restrict__ Wout, const float* __restrict__ bout,
                      float* __restrict__ out) {
    int g = blockIdx.x;
    int f = threadIdx.x & 63, sub = threadIdx.x >> 6;
    int beg = start[g], end = start[g + 1];
    float acc = 0.f;
    for (int n = beg + sub; n < end; n += 4)
        acc += b2f(h[(size_t)n * 64 + f]);
    __shared__ float red[4][64];
    red[sub][f] = acc;
    __syncthreads();
    if (sub == 0) {
        float v = red[0][f] + red[1][f] + red[2][f] + red[3][f];
        float cnt = fmaxf((float)(end - beg), 1.0f);
        red[0][f] = v / cnt;
    }
    __syncthreads();
    if (threadIdx.x < 3) {
        int o = threadIdx.x;
        float s = 0.f;
#pragma unroll
        for (int k = 0; k < 64; ++k) s += red[0][k] * Wout[k * 3 + o];
        out[g * 3 + o] = s + bout[o];
    }
}

// ---------------- launch ----------------------------------------------------

extern "C" void kernel_launch(void* const* d_in, const int* in_sizes, int n_in,
                              void* d_out, int out_size, void* d_ws, size_t ws_size,
                              hipStream_t stream)
{
    const float* x       = (const float*)d_in[0];
    const int*   ei      = (const int*)d_in[1];
    const int*   batch   = (const int*)d_in[2];
    const float* W_rel0  = (const float*)d_in[3];
    const float* b_rel0  = (const float*)d_in[4];
    const float* W_root0 = (const float*)d_in[5];
    const float* bn_g0   = (const float*)d_in[6];
    const float* bn_b0   = (const float*)d_in[7];
    const float* bn_m0   = (const float*)d_in[8];
    const float* bn_v0   = (const float*)d_in[9];
    const float* W_rel1  = (const float*)d_in[10];
    const float* b_rel1  = (const float*)d_in[11];
    const float* W_root1 = (const float*)d_in[12];
    const float* bn_g1   = (const float*)d_in[13];
    const float* bn_b1   = (const float*)d_in[14];
    const float* bn_m1   = (const float*)d_in[15];
    const float* bn_v1   = (const float*)d_in[16];
    const float* W_rel2  = (const float*)d_in[17];
    const float* b_rel2  = (const float*)d_in[18];
    const float* W_root2 = (const float*)d_in[19];
    const float* bn_g2   = (const float*)d_in[20];
    const float* bn_b2   = (const float*)d_in[21];
    const float* bn_m2   = (const float*)d_in[22];
    const float* bn_v2   = (const float*)d_in[23];
    const float* W_out   = (const float*)d_in[24];
    const float* b_out   = (const float*)d_in[25];

    const int N = in_sizes[0] / 128;
    const int E = in_sizes[1] / 2;
    const int* src = ei;
    const int* dst = ei + E;

    char* ws = (char*)d_ws;
    size_t off = 0;
    auto alloc = [&](size_t b) -> void* {
        off = (off + 255) & ~(size_t)255;
        void* p = ws + off;
        off += b;
        return p;
    };

    unsigned short* xb16   = (unsigned short*)alloc((size_t)N * 128 * 2);
    unsigned short* aggb16 = (unsigned short*)alloc((size_t)N * 128 * 2);
    unsigned short* h0     = (unsigned short*)alloc((size_t)N * 256 * 2);
    unsigned short* ycomb1 = (unsigned short*)alloc((size_t)N * 256 * 2);
    unsigned short* h1     = (unsigned short*)alloc((size_t)N * 128 * 2);
    unsigned short* ycomb2 = (unsigned short*)alloc((size_t)N * 128 * 2);
    unsigned short* h2     = (unsigned short*)alloc((size_t)N * 64 * 2);
    unsigned short* Wt0    = (unsigned short*)alloc(256 * 256 * 2);
    unsigned short* WtC1   = (unsigned short*)alloc(256 * 256 * 2);
    unsigned short* WtC2   = (unsigned short*)alloc(128 * 128 * 2);
    int* cnt    = (int*)alloc((size_t)N * 4);
    int* rowp   = (int*)alloc((size_t)(N + 1) * 4);
    int* pos    = (int*)alloc((size_t)N * 4);
    int* srcs   = (int*)alloc((size_t)E * 4);
    int* gstart = (int*)alloc(65 * 4);
    int* bsum   = (int*)alloc(1024 * 4);
    int* boff   = (int*)alloc(1024 * 4);

    hipMemsetAsync(cnt, 0, (size_t)N * 4, stream);

    const int TB = 256;
    const int egrid = (E + TB - 1) / TB;
    const int nwb = (N + 3) / 4;
    const int nsb = (N + 1023) / 1024;   // scan blocks

    hist_kernel<<<egrid, TB, 0, stream>>>(dst, cnt, E);
    scan1_kernel<<<nsb, TB, 0, stream>>>(cnt, bsum, N);
    scan2_kernel<<<1, TB, 0, stream>>>(bsum, boff, nsb);
    scan3_kernel<<<nsb, TB, 0, stream>>>(cnt, boff, rowp, pos, N);
    scatter_kernel<<<egrid, TB, 0, stream>>>(src, dst, pos, srcs, E);
    bounds_kernel<<<1, 128, 0, stream>>>(batch, gstart, N);

    conv_weights_kernel<<<576, TB, 0, stream>>>(W_rel0, W_root0, W_rel1, W_root1,
                                                W_rel2, W_root2, Wt0, WtC1, WtC2);
    conv_x_kernel<<<(N * 128 / 4 + TB - 1) / TB, TB, 0, stream>>>(x, xb16, N * 128 / 4);

    const int gx = (N + 127) / 128;

    // layer 0: agg(x) -> [agg|x] @ Wt0 (+bias,BN,ReLU) -> h0 [N,256]
    agg_bf16<128><<<nwb, TB, 0, stream>>>(xb16, 128, nullptr, 0, rowp, srcs,
                                          nullptr, nullptr, nullptr, nullptr, nullptr,
                                          aggb16, N);
    gemm_mfma<<<dim3(gx, 2), TB, 0, stream>>>(aggb16, xb16, Wt0,
                                              b_rel0, bn_g0, bn_b0, bn_m0, bn_v0,
                                              h0, N, 256, 256);

    // layer 1: ycomb1 = h0 @ [Wrel1|Wroot1]; h1 = bnrelu(agg(yrel)+yroot+b)
    gemm_mfma<<<dim3(gx, 2), TB, 0, stream>>>(h0, nullptr, WtC1,
                                              nullptr, nullptr, nullptr, nullptr, nullptr,
                                              ycomb1, N, 256, 256);
    agg_bf16<128><<<nwb, TB, 0, stream>>>(ycomb1, 256, ycomb1 + 128, 256, rowp, srcs,
                                          b_rel1, bn_g1, bn_b1, bn_m1, bn_v1,
                                          h1, N);

    // layer 2: ycomb2 = h1 @ [Wrel2|Wroot2]; h2 = bnrelu(agg(yrel)+yroot+b)
    gemm_mfma<<<dim3(gx, 1), TB, 0, stream>>>(h1, nullptr, WtC2,
                                              nullptr, nullptr, nullptr, nullptr, nullptr,
                                              ycomb2, N, 128, 128);
    agg_bf16<64><<<nwb, TB, 0, stream>>>(ycomb2, 128, ycomb2 + 64, 128, rowp, srcs,
                                         b_rel2, bn_g2, bn_b2, bn_m2, bn_v2,
                                         h2, N);

    // mean pool + head
    pool_head_kernel<<<64, TB, 0, stream>>>(h2, gstart, W_out, b_out, (float*)d_out);
}